// Round 5
// baseline (550.144 us; speedup 1.0000x reference)
//
#include <hip/hip_runtime.h>
#include <math.h>

#define C_   256
#define B_   16
#define HW_  9216
#define W_   96
#define H_   96
#define P_   16
#define EPS_ 1e-5f

typedef unsigned int u32;

// Fast exact-GELU: erf via Abramowitz-Stegun 7.1.26 (max abs err 1.5e-7,
// far inside the harness tolerance) + hardware __expf. ~15 VALU ops vs
// libm erff's much longer sequence.
__device__ __forceinline__ float gelu_f(float v)
{
    const float z = fabsf(v) * 0.70710678118654752f;
    const float t = 1.0f / fmaf(0.3275911f, z, 1.0f);
    float poly = fmaf(1.061405429f, t, -1.453152027f);
    poly = fmaf(poly, t, 1.421413741f);
    poly = fmaf(poly, t, -0.284496736f);
    poly = fmaf(poly, t, 0.254829592f);
    poly *= t;
    const float e = __expf(-z * z);
    const float er = copysignf(1.0f - poly * e, v);
    return 0.5f * v * (1.0f + er);
}

// ---------------------------------------------------------------------------
// K1: k[p][d] = sum_c proto[p][c]*k_w[d][c] + k_b[d];  v likewise.
// Block 0 also zeroes the 256-float GroupNorm sums buffer (replaces memset).
// grid: 16 blocks (p), 256 threads (d)
// ---------------------------------------------------------------------------
__global__ __launch_bounds__(256) void k_kv(
    const float* __restrict__ proto, const float* __restrict__ kw,
    const float* __restrict__ kb, const float* __restrict__ vw,
    const float* __restrict__ vb, float* __restrict__ wk, float* __restrict__ wv,
    float* __restrict__ sums)
{
    __shared__ float pr[C_];
    const int p = blockIdx.x, d = threadIdx.x;
    if (p == 0) sums[d] = 0.f;   // 128*2 floats == 256 == blockDim
    pr[d] = proto[p * C_ + d];
    __syncthreads();
    float kk = kb[d], vv = vb[d];
    const float* kr = kw + d * C_;
    const float* vr = vw + d * C_;
    #pragma unroll 8
    for (int c = 0; c < C_; ++c) {
        const float pc = pr[c];
        kk = fmaf(pc, kr[c], kk);
        vv = fmaf(pc, vr[c], vv);
    }
    wk[p * C_ + d] = kk;
    wv[p * C_ + d] = vv;
}

// ---------------------------------------------------------------------------
// K2: blocks 0..15:  m[c][p] = sum_d q_w[d][c]*k[p][d];  s0[p] = sum_d q_b[d]*k[p][d]
//     blocks 16..31: u[d][p] = sum_c v[p][c]*out_w[d][c]
// ---------------------------------------------------------------------------
__global__ __launch_bounds__(256) void k_mu(
    const float* __restrict__ wk, const float* __restrict__ wv,
    const float* __restrict__ qw, const float* __restrict__ qb,
    const float* __restrict__ ow,
    float* __restrict__ wm, float* __restrict__ wu, float* __restrict__ ws0)
{
    __shared__ float row[C_];
    __shared__ float red[C_];
    const int blk = blockIdx.x, t = threadIdx.x;
    if (blk < 16) {
        const int p = blk;
        row[t] = wk[p * C_ + t];
        __syncthreads();
        float mm = 0.f;
        #pragma unroll 8
        for (int d = 0; d < C_; ++d)
            mm = fmaf(row[d], qw[d * C_ + t], mm);
        wm[t * P_ + p] = mm;
        red[t] = qb[t] * row[t];
        __syncthreads();
        for (int s = 128; s > 0; s >>= 1) {
            if (t < s) red[t] += red[t + s];
            __syncthreads();
        }
        if (t == 0) ws0[p] = red[0];
    } else {
        const int p = blk - 16;
        row[t] = wv[p * C_ + t];
        __syncthreads();
        float uu = 0.f;
        const float* orow = ow + t * C_;
        #pragma unroll 8
        for (int c = 0; c < C_; ++c)
            uu = fmaf(row[c], orow[c], uu);
        wu[t * P_ + p] = uu;
    }
}

// ---------------------------------------------------------------------------
// K3: pd[p][n] = sum_c bilerp(pos[c])[n] * m[c][p]
// half-pixel centers, clamped edges (== jax.image.resize bilinear upsample)
// grid: 36 blocks, 256 threads (one pixel each)
// ---------------------------------------------------------------------------
__global__ __launch_bounds__(256) void k_pd(
    const float* __restrict__ pos, const float* __restrict__ m,
    float* __restrict__ pd)
{
    const int n = blockIdx.x * 256 + threadIdx.x;
    const int h = n / W_, w = n - h * W_;
    float sy = (h + 0.5f) * (2.0f / 3.0f) - 0.5f;
    float sx = (w + 0.5f) * (2.0f / 3.0f) - 0.5f;
    sy = fminf(fmaxf(sy, 0.f), 63.f);
    sx = fminf(fmaxf(sx, 0.f), 63.f);
    const int y0 = (int)sy, x0 = (int)sx;
    const float fy = sy - (float)y0, fx = sx - (float)x0;
    const int y1 = min(y0 + 1, 63), x1 = min(x0 + 1, 63);
    const float w00 = (1.f - fy) * (1.f - fx), w01 = (1.f - fy) * fx;
    const float w10 = fy * (1.f - fx),         w11 = fy * fx;
    const int i00 = y0 * 64 + x0, i01 = y0 * 64 + x1;
    const int i10 = y1 * 64 + x0, i11 = y1 * 64 + x1;

    float acc[P_];
    #pragma unroll
    for (int p = 0; p < P_; ++p) acc[p] = 0.f;

    #pragma unroll 4
    for (int c = 0; c < C_; ++c) {
        const float* pc = pos + c * 4096;
        const float pv = pc[i00] * w00 + pc[i01] * w01 +
                         pc[i10] * w10 + pc[i11] * w11;
        #pragma unroll
        for (int p = 0; p < P_; ++p)
            acc[p] = fmaf(pv, m[c * P_ + p], acc[p]);
    }
    #pragma unroll
    for (int p = 0; p < P_; ++p) pd[p * HW_ + n] = acc[p];
}

// ---------------------------------------------------------------------------
// K4a: logits + softmax only; writes the 16 attention weights per pixel to
// lw[b][p][HW] (9.4 MB). 1 px/thread, 64-thread blocks -> 2304 blocks = 9
// waves/CU exactly. 16-deep load batch -> ~36 KB/CU in flight.
// grid: 2304 blocks, 64 threads
// ---------------------------------------------------------------------------
__global__ __launch_bounds__(64) void k_logits(
    const float* __restrict__ x, const float* __restrict__ m,
    const float* __restrict__ s0, const float* __restrict__ pd,
    float* __restrict__ lw)
{
    const int n = blockIdx.x * 64 + threadIdx.x;   // 0..147455; HW%64==0 so
    const int b = n / HW_;                          // b is block-uniform
    const int npx = n - b * HW_;
    const float* xp = x + (size_t)b * (C_ * HW_) + npx;

    float acc[P_];
    #pragma unroll
    for (int p = 0; p < P_; ++p) acc[p] = 0.f;

    for (int cc = 0; cc < C_; cc += 16) {
        float xv[16];
        #pragma unroll
        for (int j = 0; j < 16; ++j)
            xv[j] = xp[(size_t)(cc + j) * HW_];
        #pragma unroll
        for (int j = 0; j < 16; ++j) {
            const float* mr = m + (cc + j) * P_;
            #pragma unroll
            for (int p = 0; p < P_; ++p)
                acc[p] = fmaf(xv[j], mr[p], acc[p]);
        }
    }

    float l[P_];
    float mx = -1e30f;
    #pragma unroll
    for (int p = 0; p < P_; ++p) {
        l[p] = (acc[p] + pd[(size_t)p * HW_ + npx] + s0[p]) * 0.0625f;
        mx = fmaxf(mx, l[p]);
    }
    float sum = 0.f;
    #pragma unroll
    for (int p = 0; p < P_; ++p) { l[p] = __expf(l[p] - mx); sum += l[p]; }
    const float r = 1.f / sum;

    float* lp = lw + (size_t)b * (P_ * HW_) + npx;
    #pragma unroll
    for (int p = 0; p < P_; ++p) lp[(size_t)p * HW_] = l[p] * r;
}

// ---------------------------------------------------------------------------
// K4b: o2[b,d,n] = ob[d] + sum_p lw[b,p,n]*u[d][p].  Each thread: 4 px
// (float4) x 8 d -> l-loads amortized 8x, u rows block-uniform (s_load).
// o2 staged in d_out (k_local reads it, writes y to ws).
// grid: (9, 32, 16), 256 threads
// ---------------------------------------------------------------------------
__global__ __launch_bounds__(256) void k_out(
    const float* __restrict__ lw, const float* __restrict__ u,
    const float* __restrict__ ob, float* __restrict__ o2)
{
    const int b = blockIdx.z;
    const int d0 = blockIdx.y * 8;
    const int px = blockIdx.x * 1024 + threadIdx.x * 4;

    const float* lp = lw + (size_t)b * (P_ * HW_) + px;
    float4 lv[P_];
    #pragma unroll
    for (int p = 0; p < P_; ++p)
        lv[p] = *reinterpret_cast<const float4*>(lp + (size_t)p * HW_);

    float* op = o2 + ((size_t)b * C_ + d0) * HW_ + px;
    #pragma unroll
    for (int j = 0; j < 8; ++j) {
        const int d = d0 + j;
        const float* ur = u + d * P_;
        const float obd = ob[d];
        float4 o = make_float4(obd, obd, obd, obd);
        #pragma unroll
        for (int p = 0; p < P_; ++p) {
            o.x = fmaf(lv[p].x, ur[p], o.x);
            o.y = fmaf(lv[p].y, ur[p], o.y);
            o.z = fmaf(lv[p].z, ur[p], o.z);
            o.w = fmaf(lv[p].w, ur[p], o.w);
        }
        *reinterpret_cast<float4*>(op + (size_t)j * HW_) = o;
    }
}

// ---------------------------------------------------------------------------
// K5: dw3x3(o2) -> BN(eval) -> fast exact GELU; y = o2+gelu+x.
// v3: HALF-plane blocks (48 rows) -> LDS tile 50x100 = 20 KB -> 8 blocks/CU
// (was 39.4 KB -> 4 blocks/CU, 33% occupancy, all pipes at ~45%).
// o2 is read from d_out; y is written to a separate ws buffer, so the
// half-plane halo rows carry no write-after-read race.
// grid: (256, 16, 2), 256 threads
// ---------------------------------------------------------------------------
__global__ __launch_bounds__(256) void k_local(
    const float* __restrict__ x, const float* __restrict__ o2,
    const float* __restrict__ dww, const float* __restrict__ bng,
    const float* __restrict__ bnb, const float* __restrict__ bnm,
    const float* __restrict__ bnv,
    float* __restrict__ y, float* __restrict__ sums)
{
    __shared__ float tile[50 * 100];   // tile row tr = image row r0-1+tr; col w+2
    const int c = blockIdx.x, b = blockIdx.y, t = threadIdx.x;
    const int r0 = blockIdx.z * 48;    // first output row of this half

    // zero halo cols (col 1 and 98; cols 0/99 are alignment pad, never read)
    if (t < 50) { tile[t * 100 + 1] = 0.f; tile[t * 100 + 98] = 0.f; }

    const size_t plane = (size_t)(b * C_ + c) * HW_;
    const float* o2p = o2 + plane;
    // fill 50 rows x 96 cols (image rows r0-1 .. r0+48; out-of-range -> 0)
    #pragma unroll
    for (int k = 0; k < 5; ++k) {
        const int g = t + k * 256;
        if (g < 1200) {
            const int tr = g / 24, wq = g - tr * 24;
            const int ir = r0 - 1 + tr;
            float4 v = make_float4(0.f, 0.f, 0.f, 0.f);
            if (ir >= 0 && ir <= 95)
                v = *reinterpret_cast<const float4*>(o2p + ir * 96 + wq * 4);
            const int base = tr * 100 + wq * 4 + 2;   // 8B-aligned
            *reinterpret_cast<float2*>(&tile[base])     = make_float2(v.x, v.y);
            *reinterpret_cast<float2*>(&tile[base + 2]) = make_float2(v.z, v.w);
        }
    }
    __syncthreads();

    const float w00 = dww[c * 9 + 0], w01 = dww[c * 9 + 1], w02 = dww[c * 9 + 2];
    const float w10 = dww[c * 9 + 3], w11 = dww[c * 9 + 4], w12 = dww[c * 9 + 5];
    const float w20 = dww[c * 9 + 6], w21 = dww[c * 9 + 7], w22 = dww[c * 9 + 8];
    const float inv  = bng[c] * rsqrtf(bnv[c] + EPS_);
    const float mu   = bnm[c];
    const float beta = bnb[c];

    const float4* xp4 = reinterpret_cast<const float4*>(x + plane);
    float4* yp4 = reinterpret_cast<float4*>(y + plane);
    float s1 = 0.f, s2 = 0.f;

    // 48 rows x 24 float4-groups = 1152 groups
    #pragma unroll
    for (int k = 0; k < 5; ++k) {
        const int g = t + k * 256;
        if (g < 1152) {
            const int lr = g / 24, wq = g - lr * 24;
            const int w0 = wq * 4;
            const int gpx = (r0 + lr) * 24 + wq;     // float4 index in plane
            const float4 xv = xp4[gpx];              // issue global load first
            const int rb = lr * 100 + w0;            // top row (image r0+lr-1)
            const float4 a0 = *reinterpret_cast<const float4*>(&tile[rb]);
            const float4 a1 = *reinterpret_cast<const float4*>(&tile[rb + 4]);
            const float4 b0 = *reinterpret_cast<const float4*>(&tile[rb + 100]);
            const float4 b1 = *reinterpret_cast<const float4*>(&tile[rb + 104]);
            const float4 c0 = *reinterpret_cast<const float4*>(&tile[rb + 200]);
            const float4 c1 = *reinterpret_cast<const float4*>(&tile[rb + 204]);
            const float A[8]  = {a0.x, a0.y, a0.z, a0.w, a1.x, a1.y, a1.z, a1.w};
            const float Bv[8] = {b0.x, b0.y, b0.z, b0.w, b1.x, b1.y, b1.z, b1.w};
            const float Cv[8] = {c0.x, c0.y, c0.z, c0.w, c1.x, c1.y, c1.z, c1.w};
            const float xs[4] = {xv.x, xv.y, xv.z, xv.w};
            float ys[4];
            #pragma unroll
            for (int j = 0; j < 4; ++j) {
                float dwv = A[j + 1] * w00 + A[j + 2] * w01 + A[j + 3] * w02
                          + Bv[j + 1] * w10 + Bv[j + 2] * w11 + Bv[j + 3] * w12
                          + Cv[j + 1] * w20 + Cv[j + 2] * w21 + Cv[j + 3] * w22;
                const float bn = (dwv - mu) * inv + beta;
                const float yv = Bv[j + 2] + gelu_f(bn) + xs[j];
                s1 += yv;
                s2 = fmaf(yv, yv, s2);
                ys[j] = yv;
            }
            yp4[gpx] = make_float4(ys[0], ys[1], ys[2], ys[3]);
        }
    }

    __syncthreads();                 // all tile reads done -> safe to alias
    float* red = tile;               // reuse LDS for the block reduction
    red[t] = s1; red[256 + t] = s2;
    __syncthreads();
    for (int s = 128; s > 0; s >>= 1) {
        if (t < s) { red[t] += red[t + s]; red[256 + t] += red[256 + t + s]; }
        __syncthreads();
    }
    if (t == 0) {
        const int bg = b * 8 + (c >> 5);
        atomicAdd(&sums[bg * 2 + 0], red[0]);
        atomicAdd(&sums[bg * 2 + 1], red[256]);
    }
}

// ---------------------------------------------------------------------------
// K6: GroupNorm normalize: read y from ws, write final result to d_out.
// grid: 36864 blocks, 256 threads (one float4/thread)
// ---------------------------------------------------------------------------
__global__ __launch_bounds__(256) void k_norm(
    const float* __restrict__ sums, const float* __restrict__ gng,
    const float* __restrict__ gnb, const float* __restrict__ ysrc,
    float* __restrict__ dst)
{
    const u32 i0 = ((u32)blockIdx.x * 256u + threadIdx.x) * 4u;
    const u32 plane = i0 / HW_;            // b*256 + c
    const u32 c = plane & 255u;
    const u32 b = plane >> 8;
    const u32 bg = b * 8u + (c >> 5);
    const float cntinv = 1.f / 294912.f;   // 32 ch * 9216 px
    const float mean = sums[bg * 2 + 0] * cntinv;
    const float var  = fmaf(sums[bg * 2 + 1], cntinv, -mean * mean);
    const float inv  = rsqrtf(var + EPS_);
    const float a  = gng[c] * inv;
    const float bb = gnb[c] - mean * a;

    float4 v = *reinterpret_cast<const float4*>(ysrc + i0);
    v.x = fmaf(v.x, a, bb);
    v.y = fmaf(v.y, a, bb);
    v.z = fmaf(v.z, a, bb);
    v.w = fmaf(v.w, a, bb);
    *reinterpret_cast<float4*>(dst + i0) = v;
}

// ---------------------------------------------------------------------------
extern "C" void kernel_launch(void* const* d_in, const int* in_sizes, int n_in,
                              void* d_out, int out_size, void* d_ws, size_t ws_size,
                              hipStream_t stream)
{
    const float* x     = (const float*)d_in[0];
    const float* proto = (const float*)d_in[1];
    const float* pos   = (const float*)d_in[2];
    const float* qw    = (const float*)d_in[3];
    const float* qb    = (const float*)d_in[4];
    const float* kw    = (const float*)d_in[5];
    const float* kb    = (const float*)d_in[6];
    const float* vw    = (const float*)d_in[7];
    const float* vb    = (const float*)d_in[8];
    const float* ow    = (const float*)d_in[9];
    const float* ob    = (const float*)d_in[10];
    const float* dww   = (const float*)d_in[11];
    const float* bng   = (const float*)d_in[12];
    const float* bnb   = (const float*)d_in[13];
    const float* bnm   = (const float*)d_in[14];
    const float* bnv   = (const float*)d_in[15];
    const float* gng   = (const float*)d_in[16];
    const float* gnb   = (const float*)d_in[17];

    char* ws = (char*)d_ws;
    float* sums = (float*)(ws);                        // 128*2*4 = 1024 B
    float* s0   = (float*)(ws + 1024);                 // 64 B
    float* wk   = (float*)(ws + 2048);                 // 16 KB
    float* wv   = (float*)(ws + 2048 + 16384);         // 16 KB
    float* wm   = (float*)(ws + 2048 + 2 * 16384);     // 16 KB  [c][p]
    float* wu   = (float*)(ws + 2048 + 3 * 16384);     // 16 KB  [d][p]
    float* pd   = (float*)(ws + 2048 + 4 * 16384);     // 576 KB [p][n]
    float* lw   = (float*)(ws + 2048 + 4 * 16384 + 589824);  // 9.4 MB [b][p][n]
    float* yws  = (float*)(ws + (size_t)16777216);     // 151 MB y staging
    // total ws usage: ~168 MB (observed ws allocation is 576 MiB)

    float* out = (float*)d_out;

    k_kv<<<16, 256, 0, stream>>>(proto, kw, kb, vw, vb, wk, wv, sums);
    k_mu<<<32, 256, 0, stream>>>(wk, wv, qw, qb, ow, wm, wu, s0);
    k_pd<<<36, 256, 0, stream>>>(pos, wm, pd);
    k_logits<<<2304, 64, 0, stream>>>(x, wm, s0, pd, lw);
    k_out<<<dim3(9, 32, 16), 256, 0, stream>>>(lw, wu, ob, out);
    k_local<<<dim3(256, 16, 2), 256, 0, stream>>>(x, out, dww, bng, bnb, bnm, bnv, yws, sums);
    k_norm<<<36864, 256, 0, stream>>>(sums, gng, gnb, yws, out);
}

// Round 7
// 524.814 us; speedup vs baseline: 1.0483x; 1.0483x over previous
//
#include <hip/hip_runtime.h>
#include <math.h>

#define C_   256
#define B_   16
#define HW_  9216
#define W_   96
#define H_   96
#define P_   16
#define EPS_ 1e-5f

typedef unsigned int u32;

// Fast exact-GELU: erf via Abramowitz-Stegun 7.1.26 (max abs err 1.5e-7) +
// hardware __expf. Correctness-verified round 5 (absmax unchanged 0.03125).
__device__ __forceinline__ float gelu_f(float v)
{
    const float z = fabsf(v) * 0.70710678118654752f;
    const float t = 1.0f / fmaf(0.3275911f, z, 1.0f);
    float poly = fmaf(1.061405429f, t, -1.453152027f);
    poly = fmaf(poly, t, 1.421413741f);
    poly = fmaf(poly, t, -0.284496736f);
    poly = fmaf(poly, t, 0.254829592f);
    poly *= t;
    const float e = __expf(-z * z);
    const float er = copysignf(1.0f - poly * e, v);
    return 0.5f * v * (1.0f + er);
}

// ---------------------------------------------------------------------------
// K1: k[p][d] = sum_c proto[p][c]*k_w[d][c] + k_b[d];  v likewise.
// Block 0 also zeroes the 256-float GroupNorm sums buffer.
// grid: 16 blocks (p), 256 threads (d)
// ---------------------------------------------------------------------------
__global__ __launch_bounds__(256) void k_kv(
    const float* __restrict__ proto, const float* __restrict__ kw,
    const float* __restrict__ kb, const float* __restrict__ vw,
    const float* __restrict__ vb, float* __restrict__ wk, float* __restrict__ wv,
    float* __restrict__ sums)
{
    __shared__ float pr[C_];
    const int p = blockIdx.x, d = threadIdx.x;
    if (p == 0) sums[d] = 0.f;   // 128*2 floats == 256 == blockDim
    pr[d] = proto[p * C_ + d];
    __syncthreads();
    float kk = kb[d], vv = vb[d];
    const float* kr = kw + d * C_;
    const float* vr = vw + d * C_;
    #pragma unroll 8
    for (int c = 0; c < C_; ++c) {
        const float pc = pr[c];
        kk = fmaf(pc, kr[c], kk);
        vv = fmaf(pc, vr[c], vv);
    }
    wk[p * C_ + d] = kk;
    wv[p * C_ + d] = vv;
}

// ---------------------------------------------------------------------------
// K2: blocks 0..15:  m[c][p] = sum_d q_w[d][c]*k[p][d];  s0[p] = sum_d q_b[d]*k[p][d]
//     blocks 16..31: u[d][p] = sum_c v[p][c]*out_w[d][c]
// ---------------------------------------------------------------------------
__global__ __launch_bounds__(256) void k_mu(
    const float* __restrict__ wk, const float* __restrict__ wv,
    const float* __restrict__ qw, const float* __restrict__ qb,
    const float* __restrict__ ow,
    float* __restrict__ wm, float* __restrict__ wu, float* __restrict__ ws0)
{
    __shared__ float row[C_];
    __shared__ float red[C_];
    const int blk = blockIdx.x, t = threadIdx.x;
    if (blk < 16) {
        const int p = blk;
        row[t] = wk[p * C_ + t];
        __syncthreads();
        float mm = 0.f;
        #pragma unroll 8
        for (int d = 0; d < C_; ++d)
            mm = fmaf(row[d], qw[d * C_ + t], mm);
        wm[t * P_ + p] = mm;
        red[t] = qb[t] * row[t];
        __syncthreads();
        for (int s = 128; s > 0; s >>= 1) {
            if (t < s) red[t] += red[t + s];
            __syncthreads();
        }
        if (t == 0) ws0[p] = red[0];
    } else {
        const int p = blk - 16;
        row[t] = wv[p * C_ + t];
        __syncthreads();
        float uu = 0.f;
        const float* orow = ow + t * C_;
        #pragma unroll 8
        for (int c = 0; c < C_; ++c)
            uu = fmaf(row[c], orow[c], uu);
        wu[t * P_ + p] = uu;
    }
}

// ---------------------------------------------------------------------------
// K3: pd[p][n] = sum_c bilerp(pos[c])[n] * m[c][p]
// grid: 36 blocks, 256 threads (one pixel each)
// ---------------------------------------------------------------------------
__global__ __launch_bounds__(256) void k_pd(
    const float* __restrict__ pos, const float* __restrict__ m,
    float* __restrict__ pd)
{
    const int n = blockIdx.x * 256 + threadIdx.x;
    const int h = n / W_, w = n - h * W_;
    float sy = (h + 0.5f) * (2.0f / 3.0f) - 0.5f;
    float sx = (w + 0.5f) * (2.0f / 3.0f) - 0.5f;
    sy = fminf(fmaxf(sy, 0.f), 63.f);
    sx = fminf(fmaxf(sx, 0.f), 63.f);
    const int y0 = (int)sy, x0 = (int)sx;
    const float fy = sy - (float)y0, fx = sx - (float)x0;
    const int y1 = min(y0 + 1, 63), x1 = min(x0 + 1, 63);
    const float w00 = (1.f - fy) * (1.f - fx), w01 = (1.f - fy) * fx;
    const float w10 = fy * (1.f - fx),         w11 = fy * fx;
    const int i00 = y0 * 64 + x0, i01 = y0 * 64 + x1;
    const int i10 = y1 * 64 + x0, i11 = y1 * 64 + x1;

    float acc[P_];
    #pragma unroll
    for (int p = 0; p < P_; ++p) acc[p] = 0.f;

    #pragma unroll 4
    for (int c = 0; c < C_; ++c) {
        const float* pc = pos + c * 4096;
        const float pv = pc[i00] * w00 + pc[i01] * w01 +
                         pc[i10] * w10 + pc[i11] * w11;
        #pragma unroll
        for (int p = 0; p < P_; ++p)
            acc[p] = fmaf(pv, m[c * P_ + p], acc[p]);
    }
    #pragma unroll
    for (int p = 0; p < P_; ++p) pd[p * HW_ + n] = acc[p];
}

// ---------------------------------------------------------------------------
// K4a: logits + softmax -> lw[b][p][HW] (9.4 MB). 2304x64 blocks = 9
// waves/CU exactly; 16-deep load batch.
// ---------------------------------------------------------------------------
__global__ __launch_bounds__(64) void k_logits(
    const float* __restrict__ x, const float* __restrict__ m,
    const float* __restrict__ s0, const float* __restrict__ pd,
    float* __restrict__ lw)
{
    const int n = blockIdx.x * 64 + threadIdx.x;
    const int b = n / HW_;
    const int npx = n - b * HW_;
    const float* xp = x + (size_t)b * (C_ * HW_) + npx;

    float acc[P_];
    #pragma unroll
    for (int p = 0; p < P_; ++p) acc[p] = 0.f;

    for (int cc = 0; cc < C_; cc += 16) {
        float xv[16];
        #pragma unroll
        for (int j = 0; j < 16; ++j)
            xv[j] = xp[(size_t)(cc + j) * HW_];
        #pragma unroll
        for (int j = 0; j < 16; ++j) {
            const float* mr = m + (cc + j) * P_;
            #pragma unroll
            for (int p = 0; p < P_; ++p)
                acc[p] = fmaf(xv[j], mr[p], acc[p]);
        }
    }

    float l[P_];
    float mx = -1e30f;
    #pragma unroll
    for (int p = 0; p < P_; ++p) {
        l[p] = (acc[p] + pd[(size_t)p * HW_ + npx] + s0[p]) * 0.0625f;
        mx = fmaxf(mx, l[p]);
    }
    float sum = 0.f;
    #pragma unroll
    for (int p = 0; p < P_; ++p) { l[p] = __expf(l[p] - mx); sum += l[p]; }
    const float r = 1.f / sum;

    float* lp = lw + (size_t)b * (P_ * HW_) + npx;
    #pragma unroll
    for (int p = 0; p < P_; ++p) lp[(size_t)p * HW_] = l[p] * r;
}

// ---------------------------------------------------------------------------
// K4b: o2[b,d,n] = ob[d] + sum_p lw[b,p,n]*u[d][p].  4 px (float4) x 16 d
// per thread (was 8: doubling d-reuse halves lw re-read traffic 300->150 MB).
// Same per-output FMA order -> bitwise-identical o2. o2 staged in d_out.
// grid: (9, 16, 16), 256 threads
// ---------------------------------------------------------------------------
__global__ __launch_bounds__(256) void k_out(
    const float* __restrict__ lw, const float* __restrict__ u,
    const float* __restrict__ ob, float* __restrict__ o2)
{
    const int b = blockIdx.z;
    const int d0 = blockIdx.y * 16;
    const int px = blockIdx.x * 1024 + threadIdx.x * 4;

    const float* lp = lw + (size_t)b * (P_ * HW_) + px;
    float4 lv[P_];
    #pragma unroll
    for (int p = 0; p < P_; ++p)
        lv[p] = *reinterpret_cast<const float4*>(lp + (size_t)p * HW_);

    float* op = o2 + ((size_t)b * C_ + d0) * HW_ + px;
    #pragma unroll
    for (int j = 0; j < 16; ++j) {
        const int d = d0 + j;
        const float* ur = u + d * P_;
        const float obd = ob[d];
        float4 o = make_float4(obd, obd, obd, obd);
        #pragma unroll
        for (int p = 0; p < P_; ++p) {
            o.x = fmaf(lv[p].x, ur[p], o.x);
            o.y = fmaf(lv[p].y, ur[p], o.y);
            o.z = fmaf(lv[p].z, ur[p], o.z);
            o.w = fmaf(lv[p].w, ur[p], o.w);
        }
        *reinterpret_cast<float4*>(op + (size_t)j * HW_) = o;
    }
}

// ---------------------------------------------------------------------------
// K5: per (b,c) plane: dw3x3(o2) -> BN(eval) -> fast GELU; y = o2+gelu+x.
// ROUND-4 MEASURED STRUCTURE (90.6 us): full-plane tile, unconditional
// unrolled loops (compiler batches the 9 global loads), in place on d_out.
// Only change: gelu_f replaces libm erff (verified round 5).
// grid: (256, 16), 256 threads
// ---------------------------------------------------------------------------
__global__ __launch_bounds__(256) void k_local(
    const float* __restrict__ x,
    const float* __restrict__ dww, const float* __restrict__ bng,
    const float* __restrict__ bnb, const float* __restrict__ bnm,
    const float* __restrict__ bnv,
    float* __restrict__ y, float* __restrict__ sums)
{
    __shared__ float tile[98 * 100];   // row r=h+1, col = w+2; cols 0,99 pad
    const int c = blockIdx.x, b = blockIdx.y, t = threadIdx.x;

    // zero halo ring (interior fully overwritten by the fill)
    if (t < 100) { tile[t] = 0.f; tile[97 * 100 + t] = 0.f; }
    if (t < 96)  { tile[(t + 1) * 100 + 1] = 0.f; tile[(t + 1) * 100 + 98] = 0.f; }

    const size_t plane = (size_t)(b * C_ + c) * HW_;
    const float4* op4 = reinterpret_cast<const float4*>(y + plane);  // o2 staged here
    #pragma unroll
    for (int k = 0; k < 9; ++k) {
        const int g = t + k * 256;           // group of 4 px; 24 groups/row
        const int h = g / 24;
        const int w0 = (g - h * 24) * 4;
        const float4 v = op4[g];
        const int base = (h + 1) * 100 + w0 + 2;   // 8B-aligned
        *reinterpret_cast<float2*>(&tile[base])     = make_float2(v.x, v.y);
        *reinterpret_cast<float2*>(&tile[base + 2]) = make_float2(v.z, v.w);
    }
    __syncthreads();

    const float w00 = dww[c * 9 + 0], w01 = dww[c * 9 + 1], w02 = dww[c * 9 + 2];
    const float w10 = dww[c * 9 + 3], w11 = dww[c * 9 + 4], w12 = dww[c * 9 + 5];
    const float w20 = dww[c * 9 + 6], w21 = dww[c * 9 + 7], w22 = dww[c * 9 + 8];
    const float inv  = bng[c] * rsqrtf(bnv[c] + EPS_);
    const float mu   = bnm[c];
    const float beta = bnb[c];

    const float4* xp4 = reinterpret_cast<const float4*>(x + plane);
    float4* yp4 = reinterpret_cast<float4*>(y + plane);
    float s1 = 0.f, s2 = 0.f;

    #pragma unroll
    for (int k = 0; k < 9; ++k) {
        const int g = t + k * 256;
        const float4 xv = xp4[g];            // issue global load first
        const int h = g / 24;
        const int w0 = (g - h * 24) * 4;
        const int r0 = h * 100 + w0;         // tile row h == image row h-1
        const float4 a0 = *reinterpret_cast<const float4*>(&tile[r0]);
        const float4 a1 = *reinterpret_cast<const float4*>(&tile[r0 + 4]);
        const float4 b0 = *reinterpret_cast<const float4*>(&tile[r0 + 100]);
        const float4 b1 = *reinterpret_cast<const float4*>(&tile[r0 + 104]);
        const float4 c0 = *reinterpret_cast<const float4*>(&tile[r0 + 200]);
        const float4 c1 = *reinterpret_cast<const float4*>(&tile[r0 + 204]);
        const float A[8]  = {a0.x, a0.y, a0.z, a0.w, a1.x, a1.y, a1.z, a1.w};
        const float Bv[8] = {b0.x, b0.y, b0.z, b0.w, b1.x, b1.y, b1.z, b1.w};
        const float Cv[8] = {c0.x, c0.y, c0.z, c0.w, c1.x, c1.y, c1.z, c1.w};
        const float xs[4] = {xv.x, xv.y, xv.z, xv.w};
        float ys[4];
        #pragma unroll
        for (int j = 0; j < 4; ++j) {        // fully unrolled -> static indices
            float dwv = A[j + 1] * w00 + A[j + 2] * w01 + A[j + 3] * w02
                      + Bv[j + 1] * w10 + Bv[j + 2] * w11 + Bv[j + 3] * w12
                      + Cv[j + 1] * w20 + Cv[j + 2] * w21 + Cv[j + 3] * w22;
            const float bn = (dwv - mu) * inv + beta;
            const float yv = Bv[j + 2] + gelu_f(bn) + xs[j];
            s1 += yv;
            s2 = fmaf(yv, yv, s2);
            ys[j] = yv;
        }
        yp4[g] = make_float4(ys[0], ys[1], ys[2], ys[3]);
    }

    __syncthreads();                 // all tile reads done -> safe to alias
    float* red = tile;               // reuse LDS for the block reduction
    red[t] = s1; red[256 + t] = s2;
    __syncthreads();
    for (int s = 128; s > 0; s >>= 1) {
        if (t < s) { red[t] += red[t + s]; red[256 + t] += red[256 + t + s]; }
        __syncthreads();
    }
    if (t == 0) {
        const int bg = b * 8 + (c >> 5);
        atomicAdd(&sums[bg * 2 + 0], red[0]);
        atomicAdd(&sums[bg * 2 + 1], red[256]);
    }
}

// ---------------------------------------------------------------------------
// K6: GroupNorm normalize, in place on d_out. 4 elems/thread (one float4).
// grid: 36864 blocks, 256 threads
// ---------------------------------------------------------------------------
__global__ __launch_bounds__(256) void k_norm(
    const float* __restrict__ sums, const float* __restrict__ gng,
    const float* __restrict__ gnb, float* __restrict__ y)
{
    const u32 i0 = ((u32)blockIdx.x * 256u + threadIdx.x) * 4u;
    const u32 plane = i0 / HW_;            // b*256 + c
    const u32 c = plane & 255u;
    const u32 b = plane >> 8;
    const u32 bg = b * 8u + (c >> 5);
    const float cntinv = 1.f / 294912.f;   // 32 ch * 9216 px
    const float mean = sums[bg * 2 + 0] * cntinv;
    const float var  = fmaf(sums[bg * 2 + 1], cntinv, -mean * mean);
    const float inv  = rsqrtf(var + EPS_);
    const float a  = gng[c] * inv;
    const float bb = gnb[c] - mean * a;

    float4 v = *reinterpret_cast<const float4*>(y + i0);
    v.x = fmaf(v.x, a, bb);
    v.y = fmaf(v.y, a, bb);
    v.z = fmaf(v.z, a, bb);
    v.w = fmaf(v.w, a, bb);
    *reinterpret_cast<float4*>(y + i0) = v;
}

// ---------------------------------------------------------------------------
extern "C" void kernel_launch(void* const* d_in, const int* in_sizes, int n_in,
                              void* d_out, int out_size, void* d_ws, size_t ws_size,
                              hipStream_t stream)
{
    const float* x     = (const float*)d_in[0];
    const float* proto = (const float*)d_in[1];
    const float* pos   = (const float*)d_in[2];
    const float* qw    = (const float*)d_in[3];
    const float* qb    = (const float*)d_in[4];
    const float* kw    = (const float*)d_in[5];
    const float* kb    = (const float*)d_in[6];
    const float* vw    = (const float*)d_in[7];
    const float* vb    = (const float*)d_in[8];
    const float* ow    = (const float*)d_in[9];
    const float* ob    = (const float*)d_in[10];
    const float* dww   = (const float*)d_in[11];
    const float* bng   = (const float*)d_in[12];
    const float* bnb   = (const float*)d_in[13];
    const float* bnm   = (const float*)d_in[14];
    const float* bnv   = (const float*)d_in[15];
    const float* gng   = (const float*)d_in[16];
    const float* gnb   = (const float*)d_in[17];

    char* ws = (char*)d_ws;
    float* sums = (float*)(ws);                        // 128*2*4 = 1024 B
    float* s0   = (float*)(ws + 1024);                 // 64 B
    float* wk   = (float*)(ws + 2048);                 // 16 KB
    float* wv   = (float*)(ws + 2048 + 16384);         // 16 KB
    float* wm   = (float*)(ws + 2048 + 2 * 16384);     // 16 KB  [c][p]
    float* wu   = (float*)(ws + 2048 + 3 * 16384);     // 16 KB  [d][p]
    float* pd   = (float*)(ws + 2048 + 4 * 16384);     // 576 KB [p][n]
    float* lw   = (float*)(ws + 2048 + 4 * 16384 + 589824);  // 9.4 MB [b][p][n]
    // total ws usage: ~10.1 MB

    float* out = (float*)d_out;

    k_kv<<<16, 256, 0, stream>>>(proto, kw, kb, vw, vb, wk, wv, sums);
    k_mu<<<32, 256, 0, stream>>>(wk, wv, qw, qb, ow, wm, wu, s0);
    k_pd<<<36, 256, 0, stream>>>(pos, wm, pd);
    k_logits<<<2304, 64, 0, stream>>>(x, wm, s0, pd, lw);
    k_out<<<dim3(9, 16, 16), 256, 0, stream>>>(lw, wu, ob, out);
    k_local<<<dim3(256, 16), 256, 0, stream>>>(x, dww, bng, bnb, bnm, bnv, out, sums);
    k_norm<<<36864, 256, 0, stream>>>(sums, gng, gnb, out);
}